// Round 7
// baseline (93.262 us; speedup 1.0000x reference)
//
#include <hip/hip_runtime.h>

// Chamfer, B=4, N=M=8192 fp32 -> scalar. Round 10: T3/T4 counted-vmcnt pipeline.
// Rounds 8/9 post-mortem: density x2 and occupancy x2 both NEUTRAL; observed ~36 us =
// SUM of pipe times (MFMA 16.6 + VALU 13.7 + LDS 8.3) and effective 949 TF == the
// documented ~900-950 TF ceiling of the 2-phase stage->vmcnt(0)->barrier structure
// (m97-class; m131-m141 show nothing inside that structure moves it). Escape per the
// catalog: counted vmcnt across raw barriers (T4, +28-41% on GEMM) + setprio (T5).
//   depth-3 ring of 8KB chunks (24KB LDS, 6 blocks/CU): iter c = wait vmcnt(2)
//   (chunk c mine done, c+1 in flight) -> s_barrier -> stage c+2 -> compute c.
//   Never vmcnt(0) in steady state; last iter peels to vmcnt(0).
// Arithmetic/mapping identical to rounds 6-9 -> absmax stays 0.

#define BATCH 4
#define NPTS 8192
#define SETPTS (BATCH * NPTS)       // 32768
#define TOTPTS (2 * SETPTS)         // 65536
#define NSLOT 32                    // bf16 K-slots per point (30 used)
#define CHUNK_PTS 128               // col points staged per chunk = 8 tiles
#define CSPLIT 8                    // col-splits per (dirb, rowblock)
#define COLS_PER (NPTS / CSPLIT)    // 1024 cols per block
#define CHUNKS_PER (COLS_PER / CHUNK_PTS)        // 8 chunks per block
#define CHUNK_BYTES (CHUNK_PTS * NSLOT * 2)      // 8192
#define DEPTH 3                     // ring-buffer depth
#define RT 4                        // row-tiles per wave
#define ROWS_BLK (4 * RT * 16)      // 256 rows per block
#define RBLK (NPTS / ROWS_BLK)      // 32 row-blocks

typedef __attribute__((ext_vector_type(8))) short bf16x8;
typedef __attribute__((ext_vector_type(4))) float f32x4;

__device__ __forceinline__ float bf16rn(float v) {  // round-to-nearest-even to bf16 value
  unsigned u = __float_as_uint(v);
  u = (u + 0x7FFFu + ((u >> 16) & 1u)) & 0xFFFF0000u;
  return __uint_as_float(u);
}
__device__ __forceinline__ unsigned short b2u(float v) {  // bf16 bits of a bf16-valued f32
  return (unsigned short)(__float_as_uint(v) >> 16);
}

// Per point: s-vec (row role, carries the -2 factor) and t-vec (col role):
//   coord d: s[8d+]: [-2a,-2a,-2a,-2b,-2b,-2b,-2c,-2c]   t[8d+]: [d,e,f,d,e,f,d,e]
//     -> limb pairs ad,ae,af,bd,be,bf,cd,ce (drops only ~2^-36 c*f)
//   slots 24-26: s = split(|p|^2), t = 1 ; slots 27-29: s = 1, t = split(|q|^2); 30-31: 0.
__global__ __launch_bounds__(256) void chamfer_prep_kernel(
    const float* __restrict__ p1, const float* __restrict__ p2,
    unsigned short* __restrict__ sArr, unsigned short* __restrict__ tArr,
    unsigned int* __restrict__ wmin, float* __restrict__ out) {
  const int i = blockIdx.x * 256 + threadIdx.x;  // 0..65535
  const float* src = (i < SETPTS) ? (p1 + 3 * (size_t)i) : (p2 + 3 * (size_t)(i - SETPTS));
  const float co[3] = {src[0], src[1], src[2]};
  union { unsigned short u[32]; uint4 v[4]; } sv, tv;
#pragma unroll
  for (int d = 0; d < 3; ++d) {
    const float v = co[d];
    const float a = bf16rn(v), r1 = v - a;        // Sterbenz-exact residuals
    const float bb = bf16rn(r1), r2 = r1 - bb;
    const float cc = bf16rn(r2);
    const unsigned short as = b2u(-2.f * a), bs = b2u(-2.f * bb), cs2 = b2u(-2.f * cc);
    const unsigned short at = b2u(a), bt = b2u(bb), ct = b2u(cc);
    sv.u[8 * d + 0] = as; sv.u[8 * d + 1] = as; sv.u[8 * d + 2] = as;
    sv.u[8 * d + 3] = bs; sv.u[8 * d + 4] = bs; sv.u[8 * d + 5] = bs;
    sv.u[8 * d + 6] = cs2; sv.u[8 * d + 7] = cs2;
    tv.u[8 * d + 0] = at; tv.u[8 * d + 1] = bt; tv.u[8 * d + 2] = ct;
    tv.u[8 * d + 3] = at; tv.u[8 * d + 4] = bt; tv.u[8 * d + 5] = ct;
    tv.u[8 * d + 6] = at; tv.u[8 * d + 7] = bt;
  }
  const float sp = fmaf(co[0], co[0], fmaf(co[1], co[1], co[2] * co[2]));
  const float g = bf16rn(sp), q1 = sp - g;
  const float h = bf16rn(q1), q2 = q1 - h;
  const float ii = bf16rn(q2);
  sv.u[24] = b2u(g); sv.u[25] = b2u(h); sv.u[26] = b2u(ii);
  tv.u[24] = 0x3F80; tv.u[25] = 0x3F80; tv.u[26] = 0x3F80;  // bf16(1.0)
  sv.u[27] = 0x3F80; sv.u[28] = 0x3F80; sv.u[29] = 0x3F80;
  tv.u[27] = b2u(g); tv.u[28] = b2u(h); tv.u[29] = b2u(ii);
  sv.u[30] = 0; sv.u[31] = 0; tv.u[30] = 0; tv.u[31] = 0;
  uint4* sd = (uint4*)(sArr + (size_t)i * NSLOT);
  uint4* td = (uint4*)(tArr + (size_t)i * NSLOT);
#pragma unroll
  for (int k = 0; k < 4; ++k) { sd[k] = sv.v[k]; td[k] = tv.v[k]; }
  wmin[i] = 0x7F800000u;  // +inf bits: > any clamped finite float's bits
  if (i == 0) out[0] = 0.f;
}

// Block: 4 waves x 4 row-tiles = 256 rows, 8 chunks (1024 cols) of its col-split.
// LDS staging via global_load_lds w=16 with pre-permuted global source (m173): LDS slot
// s holds (jt=s>>6, qr=(s>>4)&3, pt=s&15) so ds_read_b128 at lane*16 is linear
// (conflict-free) and is exactly the B-fragment (col=lane&15, k-quarter=lane>>4).
__global__ __launch_bounds__(256, 6) void chamfer_mfma_kernel(
    const unsigned short* __restrict__ sArr, const unsigned short* __restrict__ tArr,
    unsigned int* __restrict__ wmin) {
  const int bx = blockIdx.x;
  const int dirb = bx & 7;         // bx%8 -> XCD-aligned: per-XCD L2 sees one dirb's t-set
  const int rblk = (bx >> 3) & (RBLK - 1);  // 0..31 (256 rows each)
  const int csp = bx >> 8;         // 0..7 (1024 cols each)
  const int dir = dirb >> 2, b = dirb & 3;
  const unsigned short* sb = sArr + (size_t)((dir ? SETPTS : 0) + b * NPTS) * NSLOT;
  const unsigned short* tb = tArr + (size_t)((dir ? 0 : SETPTS) + b * NPTS) * NSLOT;
  unsigned int* wm = wmin + (size_t)dirb * NPTS;

  const int t = threadIdx.x;
  const int lane = t & 63, wid = t >> 6;
  const int l15 = lane & 15, l4 = lane >> 4;

  __shared__ uint4 sbuf[DEPTH][CHUNK_BYTES / 16];  // 3 x 8 KB ring
  char* cs = (char*)sbuf;

  const int rowbase = rblk * ROWS_BLK + wid * (RT * 16);  // wave owns 64 rows = 4 tiles
  bf16x8 a[RT];
#pragma unroll
  for (int m = 0; m < RT; ++m)
    a[m] = *(const bf16x8*)(sb + (size_t)(rowbase + m * 16 + l15) * NSLOT + l4 * 8);

  const char* gsrc[2];
#pragma unroll
  for (int k = 0; k < 2; ++k) {
    const int s = k * 256 + t;  // 0..511 -> 8 col-tiles per chunk
    const int jt = s >> 6, qr = (s >> 4) & 3, pt = s & 15;
    gsrc[k] = (const char*)(tb + (size_t)(csp * COLS_PER + jt * 16 + pt) * NSLOT + qr * 8);
  }

  auto stage = [&](int chunk, int buf) {
#pragma unroll
    for (int k = 0; k < 2; ++k)
      __builtin_amdgcn_global_load_lds(
          (const __attribute__((address_space(1))) void*)(gsrc[k] + (size_t)chunk * CHUNK_BYTES),
          (__attribute__((address_space(3))) void*)(cs + buf * CHUNK_BYTES + (k * 256 + t) * 16),
          16, 0, 0);
  };

  f32x4 acc[RT];
#pragma unroll
  for (int m = 0; m < RT; ++m) acc[m] = (f32x4){INFINITY, INFINITY, INFINITY, INFINITY};
  const f32x4 zero = {0.f, 0.f, 0.f, 0.f};

  stage(0, 0);  // prologue: chunks 0,1 in flight (4 loads/thread)
  stage(1, 1);

  int cbuf = 0, ibuf = 2;
  for (int c = 0; c < CHUNKS_PER; ++c) {
    // T4: counted wait -- own chunk-c loads done, chunk c+1's 2 loads stay in flight.
    if (c + 1 < CHUNKS_PER) asm volatile("s_waitcnt vmcnt(2)" ::: "memory");
    else                    asm volatile("s_waitcnt vmcnt(0)" ::: "memory");
    __builtin_amdgcn_s_barrier();        // all waves' chunk-c loads landed; readers of
    __builtin_amdgcn_sched_barrier(0);   //  chunk c-1 all done (rule-18-style pin)
    if (c + 2 < CHUNKS_PER) {            // stage into the buffer chunk c-1 vacated
      stage(c + 2, ibuf);
      ibuf = (ibuf == DEPTH - 1) ? 0 : ibuf + 1;
    }
    const char* bbase = cs + cbuf * CHUNK_BYTES + lane * 16;
    __builtin_amdgcn_s_setprio(1);       // T5: favor the MFMA cluster
#pragma unroll
    for (int jt = 0; jt < 8; jt += 2) {  // col-tile PAIRS: min3 folds two results/op
      const bf16x8 bfA = *(const bf16x8*)(bbase + jt * 1024);        // linear ds_read_b128
      const bf16x8 bfB = *(const bf16x8*)(bbase + (jt + 1) * 1024);
#pragma unroll
      for (int m = 0; m < RT; ++m) {
        const f32x4 dA = __builtin_amdgcn_mfma_f32_16x16x32_bf16(a[m], bfA, zero, 0, 0, 0);
        const f32x4 dB = __builtin_amdgcn_mfma_f32_16x16x32_bf16(a[m], bfB, zero, 0, 0, 0);
#pragma unroll
        for (int r = 0; r < 4; ++r)
          acc[m][r] = fminf(fminf(acc[m][r], dA[r]), dB[r]);  // v_min3_f32
      }
    }
    __builtin_amdgcn_s_setprio(0);
    cbuf = (cbuf == DEPTH - 1) ? 0 : cbuf + 1;
  }

  // fold the 16 col-lanes (same lane>>4 group) -> this block's row-mins
#pragma unroll
  for (int mk = 1; mk <= 8; mk <<= 1) {
#pragma unroll
    for (int m = 0; m < RT; ++m)
#pragma unroll
      for (int r = 0; r < 4; ++r)
        acc[m][r] = fminf(acc[m][r], __shfl_xor(acc[m][r], mk, 64));
  }
  if (l15 == 0) {  // C/D: col=lane&15, row=(lane>>4)*4+r [m89]
#pragma unroll
    for (int m = 0; m < RT; ++m)
#pragma unroll
      for (int r = 0; r < 4; ++r)
        atomicMin(&wm[rowbase + m * 16 + l4 * 4 + r], __float_as_uint(fmaxf(acc[m][r], 0.f)));
  }
}

__global__ __launch_bounds__(256) void chamfer_reduce_kernel(const unsigned int* __restrict__ wmin,
                                                             float* __restrict__ out) {
  // 65536 elements; 64 blocks x 256 threads x 4 elems
  float s = 0.f;
  const int base = blockIdx.x * 1024 + threadIdx.x;
#pragma unroll
  for (int k = 0; k < 4; ++k) s += __uint_as_float(wmin[base + k * 256]);
#pragma unroll
  for (int off = 32; off > 0; off >>= 1) s += __shfl_down(s, off, 64);
  __shared__ float wsum[4];
  const int lane = threadIdx.x & 63, wid = threadIdx.x >> 6;
  if (lane == 0) wsum[wid] = s;
  __syncthreads();
  if (threadIdx.x == 0) atomicAdd(out, wsum[0] + wsum[1] + wsum[2] + wsum[3]);
}

extern "C" void kernel_launch(void* const* d_in, const int* in_sizes, int n_in,
                              void* d_out, int out_size, void* d_ws, size_t ws_size,
                              hipStream_t stream) {
  const float* p1 = (const float*)d_in[0];
  const float* p2 = (const float*)d_in[1];
  float* out = (float*)d_out;
  unsigned short* sArr = (unsigned short*)d_ws;                       // 4 MB
  unsigned short* tArr = (unsigned short*)((char*)d_ws + (4 << 20));  // 4 MB
  unsigned int* wmin = (unsigned int*)((char*)d_ws + (8 << 20));      // 256 KB

  chamfer_prep_kernel<<<dim3(TOTPTS / 256), dim3(256), 0, stream>>>(p1, p2, sArr, tArr, wmin, out);
  chamfer_mfma_kernel<<<dim3(8 * RBLK * CSPLIT), dim3(256), 0, stream>>>(sArr, tArr, wmin);
  chamfer_reduce_kernel<<<dim3(64), dim3(256), 0, stream>>>(wmin, out);
}